// Round 1
// baseline (712.776 us; speedup 1.0000x reference)
//
#include <hip/hip_runtime.h>

#define SS   128   // out_size
#define DOUT 64    // out_depth
#define DIN  64    // voxel D=H=W
#define NC   16    // channels
#define NB   4     // batch

__global__ __launch_bounds__(256) void persp3d_kernel(
    const float* __restrict__ vox,
    const float* __restrict__ scale,
    const float* __restrict__ trans,
    const float* __restrict__ rot,
    const float* __restrict__ fp,
    float* __restrict__ out)
{
    const int tid = blockIdx.x * 256 + threadIdx.x;
    const int w = tid & (SS - 1);
    const int h = (tid >> 7) & (SS - 1);
    const int d = (tid >> 14) & (DOUT - 1);
    const int n = tid >> 20;

    // --- per-batch transform (tiny, L2-cached broadcast reads) ---
    const float fv  = fp[n];
    const float rho = 2.0f * fv;
    const float s0 = scale[n*3+0], s1 = scale[n*3+1], s2 = scale[n*3+2];
    const float tx = trans[n*3+0], ty = trans[n*3+1];
    const float* R = rot + n*9;   // row-major (3,3); cTw[i][j] = R[j][i]*s[j]

    // world point
    const float px = -0.5f + (float)w * (1.0f/(SS - 1));
    const float py = -0.5f + (float)h * (1.0f/(SS - 1));
    const float pz = -0.5f + (float)d * (1.0f/(DOUT - 1));

    // camera coords: cTw[:3,:3] @ p + t   (t_z = rho)
    const float cx = R[0]*s0*px + R[3]*s1*py + R[6]*s2*pz + tx;
    const float cy = R[1]*s0*px + R[4]*s1*py + R[7]*s2*pz + ty;
    const float cz = R[2]*s0*px + R[5]*s1*py + R[8]*s2*pz + rho;

    // ray grid (Z_RANGE = 1)
    const float gx = 2.0f * fv * cx / cz;
    const float gy = 2.0f * fv * cy / cz;
    const float gz = 2.0f * (cz - rho);

    // grid_sample coords, align_corners=True
    const float vx = (gx + 1.0f) * (0.5f * (DIN - 1));
    const float vy = (gy + 1.0f) * (0.5f * (DIN - 1));
    const float vz = (gz + 1.0f) * (0.5f * (DIN - 1));

    const float x0f = floorf(vx), y0f = floorf(vy), z0f = floorf(vz);
    const int   x0  = (int)x0f,   y0  = (int)y0f,   z0  = (int)z0f;
    const float fx = vx - x0f, fy = vy - y0f, fz = vz - z0f;

    float wx[2], wy[2], wz[2];
    int   xi[2], yi[2], zi[2];
    #pragma unroll
    for (int k = 0; k < 2; ++k) {
        const int ix = x0 + k, iy = y0 + k, iz = z0 + k;
        wx[k] = (ix >= 0 && ix < DIN) ? (k ? fx : 1.0f - fx) : 0.0f;
        wy[k] = (iy >= 0 && iy < DIN) ? (k ? fy : 1.0f - fy) : 0.0f;
        wz[k] = (iz >= 0 && iz < DIN) ? (k ? fz : 1.0f - fz) : 0.0f;
        xi[k] = min(max(ix, 0), DIN - 1);
        yi[k] = min(max(iy, 0), DIN - 1);
        zi[k] = min(max(iz, 0), DIN - 1);
    }

    int   idx[8];
    float wgt[8];
    #pragma unroll
    for (int kz = 0; kz < 2; ++kz)
      #pragma unroll
      for (int ky = 0; ky < 2; ++ky)
        #pragma unroll
        for (int kx = 0; kx < 2; ++kx) {
            const int k = (kz << 2) | (ky << 1) | kx;
            idx[k] = (zi[kz]*DIN + yi[ky])*DIN + xi[kx];
            wgt[k] = wz[kz]*wy[ky]*wx[kx];
        }

    const float* vb = vox + (size_t)n * NC * (DIN*DIN*DIN);
    float*       ob = out + (((size_t)(n*NC)*DOUT + d)*SS + h)*SS + w;

    #pragma unroll 4
    for (int c = 0; c < NC; ++c) {
        const float* vc = vb + (size_t)c * (DIN*DIN*DIN);
        float acc = 0.0f;
        #pragma unroll
        for (int k = 0; k < 8; ++k)
            acc += wgt[k] * vc[idx[k]];
        ob[(size_t)c * (DOUT*SS*SS)] = acc;
    }
}

extern "C" void kernel_launch(void* const* d_in, const int* in_sizes, int n_in,
                              void* d_out, int out_size, void* d_ws, size_t ws_size,
                              hipStream_t stream) {
    const float* vox   = (const float*)d_in[0];
    const float* scale = (const float*)d_in[1];
    const float* trans = (const float*)d_in[2];
    const float* rot   = (const float*)d_in[3];
    const float* f     = (const float*)d_in[4];
    float* out = (float*)d_out;

    const int total  = NB * DOUT * SS * SS;   // 4,194,304 spatial points
    const int blocks = total / 256;           // 16384
    persp3d_kernel<<<blocks, 256, 0, stream>>>(vox, scale, trans, rot, f, out);
}

// Round 2
// 173.581 us; speedup vs baseline: 4.1063x; 4.1063x over previous
//
#include <hip/hip_runtime.h>

#define SS   128   // out_size
#define DOUT 64    // out_depth
#define DIN  64    // voxel D=H=W
#define NC   16    // channels
#define NB   4     // batch
#define VOXN (DIN*DIN*DIN)

// ---------------- kernel 1: (N,C,D,H,W) -> (N,D,H,W,C) ----------------
__global__ __launch_bounds__(256) void transpose_kernel(
    const float* __restrict__ vox, float* __restrict__ wst)
{
    const int tid = blockIdx.x * 256 + threadIdx.x;   // = ((n*64+z)*64+y)*64+x
    const int x = tid & (DIN - 1);
    const int y = (tid >> 6) & (DIN - 1);
    const int z = (tid >> 12) & (DIN - 1);
    const int n = tid >> 18;

    const float* src = vox + (size_t)n * NC * VOXN + ((z * DIN + y) * DIN + x);
    float v[NC];
    #pragma unroll
    for (int c = 0; c < NC; ++c) v[c] = src[(size_t)c * VOXN];

    float4* dst = (float4*)(wst + (size_t)tid * NC);
    #pragma unroll
    for (int j = 0; j < 4; ++j)
        dst[j] = make_float4(v[4*j], v[4*j+1], v[4*j+2], v[4*j+3]);
}

// ---------------- kernel 2: sample from channels-last voxels ----------------
__global__ __launch_bounds__(256) void persp3d_cl_kernel(
    const float* __restrict__ wst,
    const float* __restrict__ scale,
    const float* __restrict__ trans,
    const float* __restrict__ rot,
    const float* __restrict__ fp,
    float* __restrict__ out)
{
    const int tid = blockIdx.x * 256 + threadIdx.x;
    const int w = tid & (SS - 1);
    const int h = (tid >> 7) & (SS - 1);
    const int d = (tid >> 14) & (DOUT - 1);
    const int n = tid >> 20;

    const float fv  = fp[n];
    const float rho = 2.0f * fv;
    const float s0 = scale[n*3+0], s1 = scale[n*3+1], s2 = scale[n*3+2];
    const float tx = trans[n*3+0], ty = trans[n*3+1];
    const float* R = rot + n*9;   // row-major (3,3); cTw[i][j] = R[j][i]*s[j]

    const float px = -0.5f + (float)w * (1.0f/(SS - 1));
    const float py = -0.5f + (float)h * (1.0f/(SS - 1));
    const float pz = -0.5f + (float)d * (1.0f/(DOUT - 1));

    const float cx = R[0]*s0*px + R[3]*s1*py + R[6]*s2*pz + tx;
    const float cy = R[1]*s0*px + R[4]*s1*py + R[7]*s2*pz + ty;
    const float cz = R[2]*s0*px + R[5]*s1*py + R[8]*s2*pz + rho;

    const float gx = 2.0f * fv * cx / cz;
    const float gy = 2.0f * fv * cy / cz;
    const float gz = 2.0f * (cz - rho);

    const float vx = (gx + 1.0f) * (0.5f * (DIN - 1));
    const float vy = (gy + 1.0f) * (0.5f * (DIN - 1));
    const float vz = (gz + 1.0f) * (0.5f * (DIN - 1));

    const float x0f = floorf(vx), y0f = floorf(vy), z0f = floorf(vz);
    const int   x0  = (int)x0f,   y0  = (int)y0f,   z0  = (int)z0f;
    const float fx = vx - x0f, fy = vy - y0f, fz = vz - z0f;

    float wx[2], wy[2], wz[2];
    int   xi[2], yi[2], zi[2];
    #pragma unroll
    for (int k = 0; k < 2; ++k) {
        const int ix = x0 + k, iy = y0 + k, iz = z0 + k;
        wx[k] = (ix >= 0 && ix < DIN) ? (k ? fx : 1.0f - fx) : 0.0f;
        wy[k] = (iy >= 0 && iy < DIN) ? (k ? fy : 1.0f - fy) : 0.0f;
        wz[k] = (iz >= 0 && iz < DIN) ? (k ? fz : 1.0f - fz) : 0.0f;
        xi[k] = min(max(ix, 0), DIN - 1);
        yi[k] = min(max(iy, 0), DIN - 1);
        zi[k] = min(max(iz, 0), DIN - 1);
    }

    const float* vb = wst + (size_t)n * VOXN * NC;

    float acc[NC];
    #pragma unroll
    for (int c = 0; c < NC; ++c) acc[c] = 0.0f;

    #pragma unroll
    for (int kz = 0; kz < 2; ++kz)
      #pragma unroll
      for (int ky = 0; ky < 2; ++ky)
        #pragma unroll
        for (int kx = 0; kx < 2; ++kx) {
            const float wgt = wz[kz] * wy[ky] * wx[kx];
            const int   idx = (zi[kz]*DIN + yi[ky])*DIN + xi[kx];
            const float4* p = (const float4*)(vb + (size_t)idx * NC);
            #pragma unroll
            for (int j = 0; j < 4; ++j) {
                const float4 v = p[j];
                acc[4*j+0] += wgt * v.x;
                acc[4*j+1] += wgt * v.y;
                acc[4*j+2] += wgt * v.z;
                acc[4*j+3] += wgt * v.w;
            }
        }

    float* ob = out + (((size_t)(n*NC)*DOUT + d)*SS + h)*SS + w;
    #pragma unroll
    for (int c = 0; c < NC; ++c)
        ob[(size_t)c * (DOUT*SS*SS)] = acc[c];
}

// ---------------- fallback (R1 kernel, channels-first) ----------------
__global__ __launch_bounds__(256) void persp3d_kernel(
    const float* __restrict__ vox,
    const float* __restrict__ scale,
    const float* __restrict__ trans,
    const float* __restrict__ rot,
    const float* __restrict__ fp,
    float* __restrict__ out)
{
    const int tid = blockIdx.x * 256 + threadIdx.x;
    const int w = tid & (SS - 1);
    const int h = (tid >> 7) & (SS - 1);
    const int d = (tid >> 14) & (DOUT - 1);
    const int n = tid >> 20;

    const float fv  = fp[n];
    const float rho = 2.0f * fv;
    const float s0 = scale[n*3+0], s1 = scale[n*3+1], s2 = scale[n*3+2];
    const float tx = trans[n*3+0], ty = trans[n*3+1];
    const float* R = rot + n*9;

    const float px = -0.5f + (float)w * (1.0f/(SS - 1));
    const float py = -0.5f + (float)h * (1.0f/(SS - 1));
    const float pz = -0.5f + (float)d * (1.0f/(DOUT - 1));

    const float cx = R[0]*s0*px + R[3]*s1*py + R[6]*s2*pz + tx;
    const float cy = R[1]*s0*px + R[4]*s1*py + R[7]*s2*pz + ty;
    const float cz = R[2]*s0*px + R[5]*s1*py + R[8]*s2*pz + rho;

    const float gx = 2.0f * fv * cx / cz;
    const float gy = 2.0f * fv * cy / cz;
    const float gz = 2.0f * (cz - rho);

    const float vx = (gx + 1.0f) * (0.5f * (DIN - 1));
    const float vy = (gy + 1.0f) * (0.5f * (DIN - 1));
    const float vz = (gz + 1.0f) * (0.5f * (DIN - 1));

    const float x0f = floorf(vx), y0f = floorf(vy), z0f = floorf(vz);
    const int   x0  = (int)x0f,   y0  = (int)y0f,   z0  = (int)z0f;
    const float fx = vx - x0f, fy = vy - y0f, fz = vz - z0f;

    float wx[2], wy[2], wz[2];
    int   xi[2], yi[2], zi[2];
    #pragma unroll
    for (int k = 0; k < 2; ++k) {
        const int ix = x0 + k, iy = y0 + k, iz = z0 + k;
        wx[k] = (ix >= 0 && ix < DIN) ? (k ? fx : 1.0f - fx) : 0.0f;
        wy[k] = (iy >= 0 && iy < DIN) ? (k ? fy : 1.0f - fy) : 0.0f;
        wz[k] = (iz >= 0 && iz < DIN) ? (k ? fz : 1.0f - fz) : 0.0f;
        xi[k] = min(max(ix, 0), DIN - 1);
        yi[k] = min(max(iy, 0), DIN - 1);
        zi[k] = min(max(iz, 0), DIN - 1);
    }

    int   idx[8];
    float wgt[8];
    #pragma unroll
    for (int kz = 0; kz < 2; ++kz)
      #pragma unroll
      for (int ky = 0; ky < 2; ++ky)
        #pragma unroll
        for (int kx = 0; kx < 2; ++kx) {
            const int k = (kz << 2) | (ky << 1) | kx;
            idx[k] = (zi[kz]*DIN + yi[ky])*DIN + xi[kx];
            wgt[k] = wz[kz]*wy[ky]*wx[kx];
        }

    const float* vb = vox + (size_t)n * NC * VOXN;
    float*       ob = out + (((size_t)(n*NC)*DOUT + d)*SS + h)*SS + w;

    #pragma unroll 4
    for (int c = 0; c < NC; ++c) {
        const float* vc = vb + (size_t)c * VOXN;
        float acc = 0.0f;
        #pragma unroll
        for (int k = 0; k < 8; ++k)
            acc += wgt[k] * vc[idx[k]];
        ob[(size_t)c * (DOUT*SS*SS)] = acc;
    }
}

extern "C" void kernel_launch(void* const* d_in, const int* in_sizes, int n_in,
                              void* d_out, int out_size, void* d_ws, size_t ws_size,
                              hipStream_t stream) {
    const float* vox   = (const float*)d_in[0];
    const float* scale = (const float*)d_in[1];
    const float* trans = (const float*)d_in[2];
    const float* rot   = (const float*)d_in[3];
    const float* f     = (const float*)d_in[4];
    float* out = (float*)d_out;

    const size_t need = (size_t)NB * VOXN * NC * sizeof(float);   // 67.1 MB
    const int total  = NB * DOUT * SS * SS;                        // 4,194,304
    const int blocks = total / 256;                                // 16384

    if (ws_size >= need) {
        float* wst = (float*)d_ws;
        const int tblocks = (NB * VOXN) / 256;                     // 4096
        transpose_kernel<<<tblocks, 256, 0, stream>>>(vox, wst);
        persp3d_cl_kernel<<<blocks, 256, 0, stream>>>(wst, scale, trans, rot, f, out);
    } else {
        persp3d_kernel<<<blocks, 256, 0, stream>>>(vox, scale, trans, rot, f, out);
    }
}

// Round 3
// 151.671 us; speedup vs baseline: 4.6995x; 1.1445x over previous
//
#include <hip/hip_runtime.h>

#define SS   128   // out_size
#define DOUT 64    // out_depth
#define DIN  64    // voxel D=H=W
#define NC   16    // channels
#define NB   4     // batch
#define VOXN (DIN*DIN*DIN)

// ---------------- kernel 1: (N,C,D,H,W) -> (N,D,H,W,C) ----------------
__global__ __launch_bounds__(256) void transpose_kernel(
    const float* __restrict__ vox, float* __restrict__ wst)
{
    const int tid = blockIdx.x * 256 + threadIdx.x;   // = ((n*64+z)*64+y)*64+x
    const float* src = vox + ((size_t)(tid >> 18)) * (NC * VOXN) + (tid & (VOXN - 1));
    float v[NC];
    #pragma unroll
    for (int c = 0; c < NC; ++c) v[c] = src[(size_t)c * VOXN];

    float4* dst = (float4*)(wst + (size_t)tid * NC);
    #pragma unroll
    for (int j = 0; j < 4; ++j)
        dst[j] = make_float4(v[4*j], v[4*j+1], v[4*j+2], v[4*j+3]);
}

// ---------------- kernel 2: channel-split sampler ----------------
// one thread = one channel-quarter (4 channels) of one output spatial point
__global__ __launch_bounds__(256) void persp3d_cq_kernel(
    const float* __restrict__ wst,
    const float* __restrict__ scale,
    const float* __restrict__ trans,
    const float* __restrict__ rot,
    const float* __restrict__ fp,
    float* __restrict__ out)
{
    const int tid = blockIdx.x * 256 + threadIdx.x;
    const int cq = tid & 3;
    const int w  = (tid >> 2)  & (SS - 1);
    const int h  = (tid >> 9)  & (SS - 1);
    const int d  = (tid >> 16) & (DOUT - 1);
    const int n  = tid >> 22;

    const float fv  = fp[n];
    const float rho = 2.0f * fv;
    const float s0 = scale[n*3+0], s1 = scale[n*3+1], s2 = scale[n*3+2];
    const float tx = trans[n*3+0], ty = trans[n*3+1];
    const float* R = rot + n*9;   // row-major (3,3); cTw[i][j] = R[j][i]*s[j]

    const float px = -0.5f + (float)w * (1.0f/(SS - 1));
    const float py = -0.5f + (float)h * (1.0f/(SS - 1));
    const float pz = -0.5f + (float)d * (1.0f/(DOUT - 1));

    const float cx = R[0]*s0*px + R[3]*s1*py + R[6]*s2*pz + tx;
    const float cy = R[1]*s0*px + R[4]*s1*py + R[7]*s2*pz + ty;
    const float cz = R[2]*s0*px + R[5]*s1*py + R[8]*s2*pz + rho;

    const float inv = 1.0f / cz;
    const float gx = 2.0f * fv * cx * inv;
    const float gy = 2.0f * fv * cy * inv;
    const float gz = 2.0f * (cz - rho);

    const float vx = (gx + 1.0f) * (0.5f * (DIN - 1));
    const float vy = (gy + 1.0f) * (0.5f * (DIN - 1));
    const float vz = (gz + 1.0f) * (0.5f * (DIN - 1));

    const float x0f = floorf(vx), y0f = floorf(vy), z0f = floorf(vz);
    const int   x0  = (int)x0f,   y0  = (int)y0f,   z0  = (int)z0f;
    const float fx = vx - x0f, fy = vy - y0f, fz = vz - z0f;

    float wx[2], wy[2], wz[2];
    int   xi[2], yi[2], zi[2];
    #pragma unroll
    for (int k = 0; k < 2; ++k) {
        const int ix = x0 + k, iy = y0 + k, iz = z0 + k;
        wx[k] = (ix >= 0 && ix < DIN) ? (k ? fx : 1.0f - fx) : 0.0f;
        wy[k] = (iy >= 0 && iy < DIN) ? (k ? fy : 1.0f - fy) : 0.0f;
        wz[k] = (iz >= 0 && iz < DIN) ? (k ? fz : 1.0f - fz) : 0.0f;
        xi[k] = min(max(ix, 0), DIN - 1);
        yi[k] = min(max(iy, 0), DIN - 1);
        zi[k] = min(max(iz, 0), DIN - 1);
    }

    // this thread's 16 B slice within each 64 B channels-last cell
    const float* vb = wst + (size_t)n * VOXN * NC + cq * 4;

    float a0 = 0.0f, a1 = 0.0f, a2 = 0.0f, a3 = 0.0f;
    #pragma unroll
    for (int kz = 0; kz < 2; ++kz)
      #pragma unroll
      for (int ky = 0; ky < 2; ++ky)
        #pragma unroll
        for (int kx = 0; kx < 2; ++kx) {
            const float wgt = wz[kz] * wy[ky] * wx[kx];
            const int   idx = (zi[kz]*DIN + yi[ky])*DIN + xi[kx];
            const float4 v = *(const float4*)(vb + (size_t)idx * NC);
            a0 += wgt * v.x;
            a1 += wgt * v.y;
            a2 += wgt * v.z;
            a3 += wgt * v.w;
        }

    // channels cq*4 .. cq*4+3, plane stride DOUT*SS*SS
    float* ob = out + (((size_t)(n*NC + cq*4)*DOUT + d)*SS + h)*SS + w;
    __builtin_nontemporal_store(a0, ob);
    __builtin_nontemporal_store(a1, ob + (size_t)1*(DOUT*SS*SS));
    __builtin_nontemporal_store(a2, ob + (size_t)2*(DOUT*SS*SS));
    __builtin_nontemporal_store(a3, ob + (size_t)3*(DOUT*SS*SS));
}

// ---------------- fallback (R1 kernel, channels-first) ----------------
__global__ __launch_bounds__(256) void persp3d_kernel(
    const float* __restrict__ vox,
    const float* __restrict__ scale,
    const float* __restrict__ trans,
    const float* __restrict__ rot,
    const float* __restrict__ fp,
    float* __restrict__ out)
{
    const int tid = blockIdx.x * 256 + threadIdx.x;
    const int w = tid & (SS - 1);
    const int h = (tid >> 7) & (SS - 1);
    const int d = (tid >> 14) & (DOUT - 1);
    const int n = tid >> 20;

    const float fv  = fp[n];
    const float rho = 2.0f * fv;
    const float s0 = scale[n*3+0], s1 = scale[n*3+1], s2 = scale[n*3+2];
    const float tx = trans[n*3+0], ty = trans[n*3+1];
    const float* R = rot + n*9;

    const float px = -0.5f + (float)w * (1.0f/(SS - 1));
    const float py = -0.5f + (float)h * (1.0f/(SS - 1));
    const float pz = -0.5f + (float)d * (1.0f/(DOUT - 1));

    const float cx = R[0]*s0*px + R[3]*s1*py + R[6]*s2*pz + tx;
    const float cy = R[1]*s0*px + R[4]*s1*py + R[7]*s2*pz + ty;
    const float cz = R[2]*s0*px + R[5]*s1*py + R[8]*s2*pz + rho;

    const float inv = 1.0f / cz;
    const float gx = 2.0f * fv * cx * inv;
    const float gy = 2.0f * fv * cy * inv;
    const float gz = 2.0f * (cz - rho);

    const float vx = (gx + 1.0f) * (0.5f * (DIN - 1));
    const float vy = (gy + 1.0f) * (0.5f * (DIN - 1));
    const float vz = (gz + 1.0f) * (0.5f * (DIN - 1));

    const float x0f = floorf(vx), y0f = floorf(vy), z0f = floorf(vz);
    const int   x0  = (int)x0f,   y0  = (int)y0f,   z0  = (int)z0f;
    const float fx = vx - x0f, fy = vy - y0f, fz = vz - z0f;

    float wx[2], wy[2], wz[2];
    int   xi[2], yi[2], zi[2];
    #pragma unroll
    for (int k = 0; k < 2; ++k) {
        const int ix = x0 + k, iy = y0 + k, iz = z0 + k;
        wx[k] = (ix >= 0 && ix < DIN) ? (k ? fx : 1.0f - fx) : 0.0f;
        wy[k] = (iy >= 0 && iy < DIN) ? (k ? fy : 1.0f - fy) : 0.0f;
        wz[k] = (iz >= 0 && iz < DIN) ? (k ? fz : 1.0f - fz) : 0.0f;
        xi[k] = min(max(ix, 0), DIN - 1);
        yi[k] = min(max(iy, 0), DIN - 1);
        zi[k] = min(max(iz, 0), DIN - 1);
    }

    int   idx[8];
    float wgt[8];
    #pragma unroll
    for (int kz = 0; kz < 2; ++kz)
      #pragma unroll
      for (int ky = 0; ky < 2; ++ky)
        #pragma unroll
        for (int kx = 0; kx < 2; ++kx) {
            const int k = (kz << 2) | (ky << 1) | kx;
            idx[k] = (zi[kz]*DIN + yi[ky])*DIN + xi[kx];
            wgt[k] = wz[kz]*wy[ky]*wx[kx];
        }

    const float* vb = vox + (size_t)n * NC * VOXN;
    float*       ob = out + (((size_t)(n*NC)*DOUT + d)*SS + h)*SS + w;

    #pragma unroll 4
    for (int c = 0; c < NC; ++c) {
        const float* vc = vb + (size_t)c * VOXN;
        float acc = 0.0f;
        #pragma unroll
        for (int k = 0; k < 8; ++k)
            acc += wgt[k] * vc[idx[k]];
        ob[(size_t)c * (DOUT*SS*SS)] = acc;
    }
}

extern "C" void kernel_launch(void* const* d_in, const int* in_sizes, int n_in,
                              void* d_out, int out_size, void* d_ws, size_t ws_size,
                              hipStream_t stream) {
    const float* vox   = (const float*)d_in[0];
    const float* scale = (const float*)d_in[1];
    const float* trans = (const float*)d_in[2];
    const float* rot   = (const float*)d_in[3];
    const float* f     = (const float*)d_in[4];
    float* out = (float*)d_out;

    const size_t need = (size_t)NB * VOXN * NC * sizeof(float);   // 67.1 MB

    if (ws_size >= need) {
        float* wst = (float*)d_ws;
        const int tblocks = (NB * VOXN) / 256;                     // 4096
        transpose_kernel<<<tblocks, 256, 0, stream>>>(vox, wst);
        const int sblocks = (NB * DOUT * SS * SS * 4) / 256;       // 65536
        persp3d_cq_kernel<<<sblocks, 256, 0, stream>>>(wst, scale, trans, rot, f, out);
    } else {
        const int blocks = (NB * DOUT * SS * SS) / 256;            // 16384
        persp3d_kernel<<<blocks, 256, 0, stream>>>(vox, scale, trans, rot, f, out);
    }
}

// Round 4
// 89.578 us; speedup vs baseline: 7.9570x; 1.6932x over previous
//
#include <hip/hip_runtime.h>
#include <hip/hip_fp16.h>

#define SS   128   // out_size
#define DOUT 64    // out_depth
#define DIN  64    // voxel D=H=W
#define NC   16    // channels
#define NB   4     // batch
#define VOXN (DIN*DIN*DIN)

typedef __attribute__((ext_vector_type(4))) unsigned int uint4v;

// -------- kernel 1: (N,C,D,H,W) f32 -> (N,D,H,W,C) fp16 --------
__global__ __launch_bounds__(256) void transpose_h_kernel(
    const float* __restrict__ vox, __half* __restrict__ wst)
{
    const int tid = blockIdx.x * 256 + threadIdx.x;   // = ((n*64+z)*64+y)*64+x
    const float* src = vox + ((size_t)(tid >> 18)) * (NC * VOXN) + (tid & (VOXN - 1));

    unsigned int u[8];
    #pragma unroll
    for (int c = 0; c < 8; ++c) {
        const float a = src[(size_t)(2*c)   * VOXN];
        const float b = src[(size_t)(2*c+1) * VOXN];
        const __half2 h = __floats2half2_rn(a, b);
        u[c] = *(const unsigned int*)&h;
    }
    uint4v* dst = (uint4v*)(wst + (size_t)tid * NC);   // 32 B per cell
    dst[0] = (uint4v){u[0], u[1], u[2], u[3]};
    dst[1] = (uint4v){u[4], u[5], u[6], u[7]};
}

// -------- kernel 2: fp16 channels-last sampler, XCD-chunked swizzle --------
// block = 256 threads = 2 channel-halves x 128 w  (one full output row)
// grid  = NB*DOUT*SS = 32768 blocks; logical id (n,d)-major so each XCD
// owns a contiguous half-batch d-slab (voxel slab ~4.2 MB, fits 4 MB L2)
__global__ __launch_bounds__(256) void persp3d_h8_kernel(
    const __half* __restrict__ wst,
    const float* __restrict__ scale,
    const float* __restrict__ trans,
    const float* __restrict__ rot,
    const float* __restrict__ fp,
    float* __restrict__ out)
{
    const int bid  = blockIdx.x;
    const int lbid = ((bid & 7) << 12) | (bid >> 3);  // bijective: 32768 % 8 == 0
    const int t   = threadIdx.x;
    const int chh = t & 1;          // channel half: 0 -> ch 0..7, 1 -> ch 8..15
    const int w   = t >> 1;         // 0..127
    const int h   = lbid & (SS - 1);
    const int d   = (lbid >> 7) & (DOUT - 1);
    const int n   = lbid >> 13;

    const float fv  = fp[n];
    const float rho = 2.0f * fv;
    const float s0 = scale[n*3+0], s1 = scale[n*3+1], s2 = scale[n*3+2];
    const float tx = trans[n*3+0], ty = trans[n*3+1];
    const float* R = rot + n*9;     // row-major (3,3); cTw[i][j] = R[j][i]*s[j]

    const float px = -0.5f + (float)w * (1.0f/(SS - 1));
    const float py = -0.5f + (float)h * (1.0f/(SS - 1));
    const float pz = -0.5f + (float)d * (1.0f/(DOUT - 1));

    const float cx = R[0]*s0*px + R[3]*s1*py + R[6]*s2*pz + tx;
    const float cy = R[1]*s0*px + R[4]*s1*py + R[7]*s2*pz + ty;
    const float cz = R[2]*s0*px + R[5]*s1*py + R[8]*s2*pz + rho;

    const float inv = 1.0f / cz;
    const float gx = 2.0f * fv * cx * inv;
    const float gy = 2.0f * fv * cy * inv;
    const float gz = 2.0f * (cz - rho);

    const float vx = (gx + 1.0f) * (0.5f * (DIN - 1));
    const float vy = (gy + 1.0f) * (0.5f * (DIN - 1));
    const float vz = (gz + 1.0f) * (0.5f * (DIN - 1));

    const float x0f = floorf(vx), y0f = floorf(vy), z0f = floorf(vz);
    const int   x0  = (int)x0f,   y0  = (int)y0f,   z0  = (int)z0f;
    const float fx = vx - x0f, fy = vy - y0f, fz = vz - z0f;

    float wx[2], wy[2], wz[2];
    int   xi[2], yi[2], zi[2];
    #pragma unroll
    for (int k = 0; k < 2; ++k) {
        const int ix = x0 + k, iy = y0 + k, iz = z0 + k;
        wx[k] = (ix >= 0 && ix < DIN) ? (k ? fx : 1.0f - fx) : 0.0f;
        wy[k] = (iy >= 0 && iy < DIN) ? (k ? fy : 1.0f - fy) : 0.0f;
        wz[k] = (iz >= 0 && iz < DIN) ? (k ? fz : 1.0f - fz) : 0.0f;
        xi[k] = min(max(ix, 0), DIN - 1);
        yi[k] = min(max(iy, 0), DIN - 1);
        zi[k] = min(max(iz, 0), DIN - 1);
    }

    // this thread's 16 B slice (8 fp16 channels) within each 32 B cell
    const __half* vb = wst + (size_t)n * VOXN * NC + chh * 8;

    float acc[8];
    #pragma unroll
    for (int c = 0; c < 8; ++c) acc[c] = 0.0f;

    #pragma unroll
    for (int kz = 0; kz < 2; ++kz)
      #pragma unroll
      for (int ky = 0; ky < 2; ++ky)
        #pragma unroll
        for (int kx = 0; kx < 2; ++kx) {
            const float wgt = wz[kz] * wy[ky] * wx[kx];
            const int   idx = (zi[kz]*DIN + yi[ky])*DIN + xi[kx];
            const uint4v r = *(const uint4v*)(vb + (size_t)idx * NC);
            #pragma unroll
            for (int j = 0; j < 4; ++j) {
                const unsigned int uu = r[j];
                const float2 f2 = __half22float2(*(const __half2*)&uu);
                acc[2*j+0] += wgt * f2.x;
                acc[2*j+1] += wgt * f2.y;
            }
        }

    float* ob = out + (((size_t)(n*NC + chh*8)*DOUT + d)*SS + h)*SS + w;
    #pragma unroll
    for (int j = 0; j < 8; ++j)
        __builtin_nontemporal_store(acc[j], ob + (size_t)j * (DOUT*SS*SS));
}

// ---------------- fallback (channels-first, no workspace) ----------------
__global__ __launch_bounds__(256) void persp3d_kernel(
    const float* __restrict__ vox,
    const float* __restrict__ scale,
    const float* __restrict__ trans,
    const float* __restrict__ rot,
    const float* __restrict__ fp,
    float* __restrict__ out)
{
    const int tid = blockIdx.x * 256 + threadIdx.x;
    const int w = tid & (SS - 1);
    const int h = (tid >> 7) & (SS - 1);
    const int d = (tid >> 14) & (DOUT - 1);
    const int n = tid >> 20;

    const float fv  = fp[n];
    const float rho = 2.0f * fv;
    const float s0 = scale[n*3+0], s1 = scale[n*3+1], s2 = scale[n*3+2];
    const float tx = trans[n*3+0], ty = trans[n*3+1];
    const float* R = rot + n*9;

    const float px = -0.5f + (float)w * (1.0f/(SS - 1));
    const float py = -0.5f + (float)h * (1.0f/(SS - 1));
    const float pz = -0.5f + (float)d * (1.0f/(DOUT - 1));

    const float cx = R[0]*s0*px + R[3]*s1*py + R[6]*s2*pz + tx;
    const float cy = R[1]*s0*px + R[4]*s1*py + R[7]*s2*pz + ty;
    const float cz = R[2]*s0*px + R[5]*s1*py + R[8]*s2*pz + rho;

    const float inv = 1.0f / cz;
    const float gx = 2.0f * fv * cx * inv;
    const float gy = 2.0f * fv * cy * inv;
    const float gz = 2.0f * (cz - rho);

    const float vx = (gx + 1.0f) * (0.5f * (DIN - 1));
    const float vy = (gy + 1.0f) * (0.5f * (DIN - 1));
    const float vz = (gz + 1.0f) * (0.5f * (DIN - 1));

    const float x0f = floorf(vx), y0f = floorf(vy), z0f = floorf(vz);
    const int   x0  = (int)x0f,   y0  = (int)y0f,   z0  = (int)z0f;
    const float fx = vx - x0f, fy = vy - y0f, fz = vz - z0f;

    float wx[2], wy[2], wz[2];
    int   xi[2], yi[2], zi[2];
    #pragma unroll
    for (int k = 0; k < 2; ++k) {
        const int ix = x0 + k, iy = y0 + k, iz = z0 + k;
        wx[k] = (ix >= 0 && ix < DIN) ? (k ? fx : 1.0f - fx) : 0.0f;
        wy[k] = (iy >= 0 && iy < DIN) ? (k ? fy : 1.0f - fy) : 0.0f;
        wz[k] = (iz >= 0 && iz < DIN) ? (k ? fz : 1.0f - fz) : 0.0f;
        xi[k] = min(max(ix, 0), DIN - 1);
        yi[k] = min(max(iy, 0), DIN - 1);
        zi[k] = min(max(iz, 0), DIN - 1);
    }

    int   idx[8];
    float wgt[8];
    #pragma unroll
    for (int kz = 0; kz < 2; ++kz)
      #pragma unroll
      for (int ky = 0; ky < 2; ++ky)
        #pragma unroll
        for (int kx = 0; kx < 2; ++kx) {
            const int k = (kz << 2) | (ky << 1) | kx;
            idx[k] = (zi[kz]*DIN + yi[ky])*DIN + xi[kx];
            wgt[k] = wz[kz]*wy[ky]*wx[kx];
        }

    const float* vb = vox + (size_t)n * NC * VOXN;
    float*       ob = out + (((size_t)(n*NC)*DOUT + d)*SS + h)*SS + w;

    #pragma unroll 4
    for (int c = 0; c < NC; ++c) {
        const float* vc = vb + (size_t)c * VOXN;
        float acc = 0.0f;
        #pragma unroll
        for (int k = 0; k < 8; ++k)
            acc += wgt[k] * vc[idx[k]];
        ob[(size_t)c * (DOUT*SS*SS)] = acc;
    }
}

extern "C" void kernel_launch(void* const* d_in, const int* in_sizes, int n_in,
                              void* d_out, int out_size, void* d_ws, size_t ws_size,
                              hipStream_t stream) {
    const float* vox   = (const float*)d_in[0];
    const float* scale = (const float*)d_in[1];
    const float* trans = (const float*)d_in[2];
    const float* rot   = (const float*)d_in[3];
    const float* f     = (const float*)d_in[4];
    float* out = (float*)d_out;

    const size_t need = (size_t)NB * VOXN * NC * sizeof(__half);   // 33.5 MB

    if (ws_size >= need) {
        __half* wst = (__half*)d_ws;
        const int tblocks = (NB * VOXN) / 256;                     // 4096
        transpose_h_kernel<<<tblocks, 256, 0, stream>>>(vox, wst);
        const int sblocks = NB * DOUT * SS;                        // 32768
        persp3d_h8_kernel<<<sblocks, 256, 0, stream>>>(wst, scale, trans, rot, f, out);
    } else {
        const int blocks = (NB * DOUT * SS * SS) / 256;            // 16384
        persp3d_kernel<<<blocks, 256, 0, stream>>>(vox, scale, trans, rot, f, out);
    }
}